// Round 11
// baseline (56.603 us; speedup 1.0000x reference)
//
#include <hip/hip_runtime.h>
#include <hip/hip_bf16.h>

#define T_DIM 6
#define N_NODES 10000
#define TOTAL_ROWS (T_DIM * N_NODES)   // 60000
#define LOG2E 1.44269504088896340736f
#define QPRE (0.25f * LOG2E)           // dh^-0.5 * log2(e): softmax done in exp2 domain
#define EPS_GATE 1e-6f
#define NEGBIG (-1e30f)
#define CAP 64                         // max in-degree supported (Poisson(5); guarded)
// record stride in u16: KV-interleaved [t][64][2] = 768 u16 | gate[6] f32 (=12 u16) | pad
#define REC 832                        // 1664 B, 64B-aligned

typedef unsigned int u32;
typedef unsigned short u16;
typedef __attribute__((ext_vector_type(8))) short bf16x8;
typedef __attribute__((ext_vector_type(4))) float f32x4;

#define MFMA16(a, b, c) __builtin_amdgcn_mfma_f32_16x16x32_bf16(a, b, c, 0, 0, 0)

__device__ __forceinline__ float fast_exp2(float x) {
#if __has_builtin(__builtin_amdgcn_exp2f)
    return __builtin_amdgcn_exp2f(x);
#else
    return exp2f(x);
#endif
}

// DPP butterfly add within 4-lane quads.
template <int CTRL>
__device__ __forceinline__ float dpp_add(float x) {
    int v = __builtin_amdgcn_update_dpp(0, __float_as_int(x), CTRL, 0xf, 0xf, true);
    return x + __int_as_float(v);
}
__device__ __forceinline__ float red4(float x) {
    x = dpp_add<0xB1>(x);   // quad_perm {1,0,3,2} : lane ^ 1
    x = dpp_add<0x4E>(x);   // quad_perm {2,3,0,1} : lane ^ 2
    return x;               // all 4 lanes of the quad hold the sum
}

__device__ __forceinline__ float bf2f(u16 u) {
    union { unsigned int i; float f; } c;
    c.i = ((unsigned int)u) << 16;
    return c.f;
}

__device__ __forceinline__ u16 f2bf(float f) {
    union { float f; unsigned int i; } c; c.f = f;
    unsigned int i = c.i;
    unsigned int lsb = (i >> 16) & 1u;
    i += 0x7FFFu + lsb;          // round-to-nearest-even (finite data only)
    return (u16)(i >> 16);
}

// ------- K1: cursor zero + gate-into-record + kpe/bias tables + MFMA QKV projection -------
// Q (bf16, prescaled QPRE) -> Qb [t][n][64].  K/V (bf16, dim-interleaved) + gate (f32) -> KVG [n].
__global__ __launch_bounds__(256) void proj_kernel(
    const float* __restrict__ H,
    const float* __restrict__ S,
    const float* __restrict__ Wq, const float* __restrict__ Wk,
    const float* __restrict__ Wv,
    int* __restrict__ cursor,
    u16* __restrict__ Qb, u16* __restrict__ KVG,
    float* __restrict__ kpe, float* __restrict__ bias) {
    int tid = threadIdx.x;
    int gtid = blockIdx.x * 256 + tid;
    // ---- prep: zero cursor; gate rows (24B contiguous per record) ----
    if (gtid < N_NODES) {
        cursor[gtid] = 0;
        float* gp = (float*)(KVG + (size_t)gtid * REC + 768);
        #pragma unroll
        for (int t = 0; t < T_DIM; ++t)
            gp[t] = log2f(S[t * N_NODES + gtid] + EPS_GATE);
    }
    if (blockIdx.x == 0 && tid < 64) {
        int c = tid;
        for (int dt = 0; dt < 9; ++dt) {
            float fdt = (float)dt;
            float pe[8];
            pe[0] = expf(-fdt * 0.25f);    // tau=4
            pe[1] = expf(-fdt * 0.0625f);  // tau=16
            pe[2] = sinf(fdt * 1.0f);
            pe[3] = sinf(fdt * 0.5f);
            pe[4] = sinf(fdt * 0.25f);
            pe[5] = cosf(fdt * 1.0f);
            pe[6] = cosf(fdt * 0.5f);
            pe[7] = cosf(fdt * 0.25f);
            float acc = 0.f;
            #pragma unroll
            for (int j = 0; j < 8; ++j) acc += pe[j] * Wk[c * 72 + 64 + j];
            kpe[dt * 64 + c] = acc;
            if (c == 0) bias[dt] = -log2f(1.0f + fdt);
        }
    }

    // ---- weight staging ----
    __shared__ short whi[192][72];   // stride 72 shorts = 144B -> 2-way banks (free)
    __shared__ short wlo[192][72];
    for (int i = tid; i < 192 * 64; i += 256) {
        int col = i >> 6, k = i & 63;
        float w;
        if (col < 64)       w = Wq[col * 64 + k];
        else if (col < 128) w = Wk[(col - 64) * 72 + k];   // first 64 input dims of W_k
        else                w = Wv[(col - 128) * 64 + k];
        u16 hb = f2bf(w);
        whi[col][k] = (short)hb;
        wlo[col][k] = (short)f2bf(w - bf2f(hb));
    }
    __syncthreads();

    int lane = tid & 63, wid = tid >> 6;
    int r0 = (blockIdx.x * 4 + wid) * 32;          // 32 rows per wave (60000 = 32*1875)
    if (r0 >= TOTAL_ROWS) return;

    int mrow = lane & 15;
    int kgrp = lane >> 4;                          // 0..3

    // A fragments: [mtile][kstep], hi+lo split (f32 accuracy: h*w ~= hi*whi + hi*wlo + lo*whi)
    bf16x8 ahi[2][2], alo[2][2];
    #pragma unroll
    for (int mt = 0; mt < 2; ++mt) {
        #pragma unroll
        for (int ks = 0; ks < 2; ++ks) {
            const float* hp = H + (size_t)(r0 + mt * 16 + mrow) * 64 + ks * 32 + kgrp * 8;
            float4 hA = *(const float4*)hp;
            float4 hB = *(const float4*)(hp + 4);
            float tmp[8] = {hA.x, hA.y, hA.z, hA.w, hB.x, hB.y, hB.z, hB.w};
            #pragma unroll
            for (int b = 0; b < 8; ++b) {
                u16 hb = f2bf(tmp[b]);
                ahi[mt][ks][b] = (short)hb;
                alo[mt][ks][b] = (short)f2bf(tmp[b] - bf2f(hb));
            }
        }
    }

    float kbuf[2][4][4];   // buffered K accs [mt][j][c4]; static indices only (rule #20)

    #pragma unroll
    for (int nt = 0; nt < 12; ++nt) {
        f32x4 acc0 = {0.f, 0.f, 0.f, 0.f};
        f32x4 acc1 = {0.f, 0.f, 0.f, 0.f};
        #pragma unroll
        for (int ks = 0; ks < 2; ++ks) {
            bf16x8 bh = *(const bf16x8*)&whi[nt * 16 + mrow][ks * 32 + kgrp * 8];
            bf16x8 bl = *(const bf16x8*)&wlo[nt * 16 + mrow][ks * 32 + kgrp * 8];
            acc0 = MFMA16(ahi[0][ks], bh, acc0);
            acc0 = MFMA16(ahi[0][ks], bl, acc0);
            acc0 = MFMA16(alo[0][ks], bh, acc0);
            acc1 = MFMA16(ahi[1][ks], bh, acc1);
            acc1 = MFMA16(ahi[1][ks], bl, acc1);
            acc1 = MFMA16(alo[1][ks], bh, acc1);
        }
        // epilogue: C col = lane&15, row = (lane>>4)*4 + j   [m89-verified]
        // K-pass (nt 4-7) buffers to registers; V-pass (nt 8-11) emits packed 4B KV stores.
        #pragma unroll
        for (int mt = 0; mt < 2; ++mt) {
            f32x4 acc = mt ? acc1 : acc0;
            int mbase = r0 + mt * 16 + kgrp * 4;
            #pragma unroll
            for (int j = 0; j < 4; ++j) {
                int gr = mbase + j;
                float v = acc[j];
                if (nt < 4) {
                    Qb[(size_t)gr * 64 + (nt & 3) * 16 + mrow] = f2bf(v * QPRE);
                } else if (nt < 8) {
                    kbuf[mt][j][nt - 4] = v;
                } else {
                    int t = gr / N_NODES, n = gr - t * N_NODES;
                    int col = (nt & 3) * 16 + mrow;
                    u32 pack = (u32)f2bf(kbuf[mt][j][nt - 8]) | ((u32)f2bf(v) << 16);
                    *(u32*)(KVG + (size_t)n * REC + t * 128 + col * 2) = pack;
                }
            }
        }
    }
}

// ------- K2: scatter edges into fixed-capacity per-dst slots (atomic = hist + rank) -------
__global__ void scatter_kernel(const int* __restrict__ esrc, const int* __restrict__ edst,
                               int* __restrict__ cursor, int* __restrict__ slots, int E) {
    int e = blockIdx.x * blockDim.x + threadIdx.x;
    if (e < E) {
        int d = edst[e];
        int pos = atomicAdd(&cursor[d], 1);
        if (pos < CAP) slots[d * CAP + pos] = esrc[e];
    }
}

// ------- K3: aggregation: one wave per node, 4 edges/iter, KV-interleaved dwordx4 gather -------
// lane = e4*16 + (h*4 + dg) : edge-group(4) x [head(4) x dim-quad(4)]; lane owns 4 dims.
__global__ __launch_bounds__(128) void agg_kernel(
    const u16* __restrict__ Qb,       // [t][n][64] bf16, prescaled QPRE
    const u16* __restrict__ KVG,      // per-node records, KV interleaved
    const float* __restrict__ kpe,    // [9][64]
    const float* __restrict__ bias,   // [9]  -log2(1+dt)
    const int* __restrict__ deg_arr,  // cursor = in-degree
    const int* __restrict__ slots,    // [n][CAP]
    float* __restrict__ out) {
    int lane = threadIdx.x & 63, w = threadIdx.x >> 6;
    int n = blockIdx.x * 2 + w;
    int e4 = lane >> 4;                      // which of 4 edges
    int doff = (lane & 15) << 2;             // dim offset, 4 dims per lane

    // issue independent loads up front (deg is the only branch dependency)
    int deg = deg_arr[n];
    int slotv = slots[n * CAP + lane];       // ALL edge indices in one coalesced load
    uint2 qraw[T_DIM];
    #pragma unroll
    for (int t = 0; t < T_DIM; ++t)
        qraw[t] = *(const uint2*)(Qb + ((size_t)t * N_NODES + n) * 64 + doff);

    if (deg <= 0) {                          // zero-degree: output 0 (matches ref clip)
        if (e4 == 0) {
            #pragma unroll
            for (int t = 0; t < T_DIM; ++t)
                *(float4*)(out + ((size_t)t * N_NODES + n) * 64 + doff) =
                    make_float4(0.f, 0.f, 0.f, 0.f);
        }
        return;
    }
    deg = min(deg, CAP);
    int ng = (deg + 3) >> 2;

    uint4 kvA[T_DIM], kvB[T_DIM];
    float ggA[T_DIM], ggB[T_DIM];

#define LOADG(BASE, KV, GG) {                                                   \
        int eidx = (BASE) + e4;                                                 \
        int sidx = __shfl(slotv, min(eidx, deg - 1));                           \
        const u16* bp = KVG + (size_t)sidx * REC;                               \
        _Pragma("unroll")                                                       \
        for (int t = 0; t < T_DIM; ++t)                                         \
            KV[t] = *(const uint4*)(bp + t * 128 + doff * 2);                   \
        const float* gp = (const float*)(bp + 768);                             \
        float4 gA = *(const float4*)gp;                                         \
        float2 gB = *(const float2*)(gp + 4);                                   \
        bool val = eidx < deg;                                                  \
        GG[0] = val ? gA.x : NEGBIG; GG[1] = val ? gA.y : NEGBIG;               \
        GG[2] = val ? gA.z : NEGBIG; GG[3] = val ? gA.w : NEGBIG;               \
        GG[4] = val ? gB.x : NEGBIG; GG[5] = val ? gB.y : NEGBIG;               \
    }

    // preload groups 0 and 1 (both in flight before any compute)
    LOADG(0, kvA, ggA);
    if (ng > 1) LOADG(4, kvB, ggB);

    // unpack q + compute cc while the gathers are in flight
    float4 q[T_DIM];
    #pragma unroll
    for (int t = 0; t < T_DIM; ++t) {
        q[t].x = bf2f((u16)(qraw[t].x & 0xffff));
        q[t].y = bf2f((u16)(qraw[t].x >> 16));
        q[t].z = bf2f((u16)(qraw[t].y & 0xffff));
        q[t].w = bf2f((u16)(qraw[t].y >> 16));
    }
    float cc[21];   // cc[tri(t,dt)] = dot16(q[t], K_pe[dt]) + bias[dt]  (uniform per quad)
    #pragma unroll
    for (int dt = 0; dt < T_DIM; ++dt) {
        float4 kp = *(const float4*)(kpe + dt * 64 + doff);
        float b = bias[dt];
        #pragma unroll
        for (int t = dt; t < T_DIM; ++t) {
            float part = q[t].x * kp.x;
            part = fmaf(q[t].y, kp.y, part);
            part = fmaf(q[t].z, kp.z, part);
            part = fmaf(q[t].w, kp.w, part);
            cc[t * (t + 1) / 2 + dt] = red4(part) + b;
        }
    }

    float den[T_DIM] = {0,0,0,0,0,0};
    float4 nu[T_DIM];
    #pragma unroll
    for (int t = 0; t < T_DIM; ++t) nu[t] = make_float4(0.f, 0.f, 0.f, 0.f);

    for (int g = 0; ; ++g) {
        // ---- compute current group from A buffers: tp-outer, one KV row unpacked at a time ----
        #pragma unroll
        for (int tp = 0; tp < T_DIM; ++tp) {
            uint4 x = kvA[tp];
            float k0 = bf2f((u16)(x.x & 0xffff)), v0 = bf2f((u16)(x.x >> 16));
            float k1 = bf2f((u16)(x.y & 0xffff)), v1 = bf2f((u16)(x.y >> 16));
            float k2 = bf2f((u16)(x.z & 0xffff)), v2 = bf2f((u16)(x.z >> 16));
            float k3 = bf2f((u16)(x.w & 0xffff)), v3 = bf2f((u16)(x.w >> 16));
            float gv = ggA[tp];
            #pragma unroll
            for (int t = tp; t < T_DIM; ++t) {
                int dt = t - tp;
                float part = q[t].x * k0;
                part = fmaf(q[t].y, k1, part);
                part = fmaf(q[t].z, k2, part);
                part = fmaf(q[t].w, k3, part);
                float wt = fast_exp2(red4(part) + cc[t * (t + 1) / 2 + dt] + gv);
                den[t] += wt;
                nu[t].x = fmaf(wt, v0, nu[t].x);
                nu[t].y = fmaf(wt, v1, nu[t].y);
                nu[t].z = fmaf(wt, v2, nu[t].z);
                nu[t].w = fmaf(wt, v3, nu[t].w);
            }
        }
        if (g + 1 >= ng) break;
        #pragma unroll
        for (int t = 0; t < T_DIM; ++t) { kvA[t] = kvB[t]; ggA[t] = ggB[t]; }
        if (g + 2 < ng) LOADG((g + 2) * 4, kvB, ggB);   // wave-uniform gate: no wasted groups
    }
#undef LOADG

    // combine the four edge-groups (once per node), then store
    #pragma unroll
    for (int t = 0; t < T_DIM; ++t) {
        den[t] += __shfl_xor(den[t], 16);  den[t] += __shfl_xor(den[t], 32);
        nu[t].x += __shfl_xor(nu[t].x, 16); nu[t].x += __shfl_xor(nu[t].x, 32);
        nu[t].y += __shfl_xor(nu[t].y, 16); nu[t].y += __shfl_xor(nu[t].y, 32);
        nu[t].z += __shfl_xor(nu[t].z, 16); nu[t].z += __shfl_xor(nu[t].z, 32);
        nu[t].w += __shfl_xor(nu[t].w, 16); nu[t].w += __shfl_xor(nu[t].w, 32);
    }
    if (e4 == 0) {
        #pragma unroll
        for (int t = 0; t < T_DIM; ++t) {
            float r = 1.0f / fmaxf(den[t], 1e-12f);
            *(float4*)(out + ((size_t)t * N_NODES + n) * 64 + doff) =
                make_float4(nu[t].x * r, nu[t].y * r, nu[t].z * r, nu[t].w * r);
        }
    }
}

extern "C" void kernel_launch(void* const* d_in, const int* in_sizes, int n_in,
                              void* d_out, int out_size, void* d_ws, size_t ws_size,
                              hipStream_t stream) {
    const float* H  = (const float*)d_in[0];
    const float* S  = (const float*)d_in[1];
    const float* Wq = (const float*)d_in[2];
    const float* Wk = (const float*)d_in[3];
    const float* Wv = (const float*)d_in[4];
    const int* edge = (const int*)d_in[5];
    int E = in_sizes[5] / 2;
    const int* esrc = edge;
    const int* edst = edge + E;
    float* out = (float*)d_out;

    char* ws = (char*)d_ws;
    size_t off = 0;
    auto alloc = [&](size_t b) { char* p = ws + off; off += (b + 255) & ~(size_t)255; return (void*)p; };
    u16*   KVG     = (u16*)  alloc((size_t)N_NODES * REC * 2);    // 16.64 MB records
    u16*   Qb      = (u16*)  alloc((size_t)TOTAL_ROWS * 64 * 2);  // 7.68 MB
    int*   cursor  = (int*)  alloc((size_t)N_NODES * 4);          // degree + scatter rank
    int*   slots   = (int*)  alloc((size_t)N_NODES * CAP * 4);    // 2.56 MB edge lists
    float* kpe     = (float*)alloc(9 * 64 * 4);
    float* bias    = (float*)alloc(9 * 4);

    int proj_blocks = (TOTAL_ROWS / 32 + 3) / 4;   // 469
    proj_kernel<<<proj_blocks, 256, 0, stream>>>(H, S, Wq, Wk, Wv, cursor, Qb, KVG, kpe, bias);
    scatter_kernel<<<(E + 255) / 256, 256, 0, stream>>>(esrc, edst, cursor, slots, E);
    agg_kernel<<<(N_NODES + 1) / 2, 128, 0, stream>>>(Qb, KVG, kpe, bias, cursor, slots, out);
}